// Round 1
// baseline (535.257 us; speedup 1.0000x reference)
//
#include <hip/hip_runtime.h>

// Problem constants (match reference setup_inputs)
#define N 16384
#define CAP 64   // max nnz tracked per row/column of H (Poisson(17) -> max ~40)

// ---------------------------------------------------------------------------
// Zero the count arrays (row_cnt, col_cnt) each call.
__global__ void k_zero(int* __restrict__ p, int n) {
    int i = blockIdx.x * blockDim.x + threadIdx.x;
    if (i < n) p[i] = 0;
}

// ---------------------------------------------------------------------------
// Single streaming pass over dense H (1 GiB):
//  - builds CSR (rowIdx, row_cnt): for node v, list of incident edges e
//  - builds CSC (colIdx, col_cnt): for edge e, list of member nodes v
// H is binary, so counts == degree sums.
__global__ void k_scan_H(const float* __restrict__ H,
                         int* __restrict__ row_cnt, int* __restrict__ col_cnt,
                         int* __restrict__ rowIdx, int* __restrict__ colIdx) {
    __shared__ int rc;
    int v = blockIdx.x;
    if (threadIdx.x == 0) rc = 0;
    __syncthreads();
    const float4* row = reinterpret_cast<const float4*>(H + (size_t)v * N);
    #pragma unroll 4
    for (int i = 0; i < 16; ++i) {
        int idx4 = i * 256 + threadIdx.x;
        float4 val = row[idx4];
        int e0 = idx4 * 4;
        float vals[4] = {val.x, val.y, val.z, val.w};
        #pragma unroll
        for (int j = 0; j < 4; ++j) {
            if (vals[j] != 0.0f) {
                int e = e0 + j;
                int p = atomicAdd(&rc, 1);
                if (p < CAP) rowIdx[(size_t)v * CAP + p] = e;
                int q = atomicAdd(&col_cnt[e], 1);
                if (q < CAP) colIdx[(size_t)e * CAP + q] = v;
            }
        }
    }
    __syncthreads();
    if (threadIdx.x == 0) row_cnt[v] = rc;
}

// dv_inv = 1/row_cnt, de_inv = 1/col_cnt (self-loop guarantees cnt >= 1)
__global__ void k_inv(const int* __restrict__ rc, const int* __restrict__ cc,
                      float* __restrict__ dv, float* __restrict__ de) {
    int i = blockIdx.x * blockDim.x + threadIdx.x;
    if (i < N) {
        dv[i] = 1.0f / (float)rc[i];
        de[i] = 1.0f / (float)cc[i];
    }
}

// ---------------------------------------------------------------------------
// y0[v,c] = risk[v] * ltheta0[0,c] + lbias0[c]   (N x 64)
__global__ void k_outer_label(const float* __restrict__ risk,
                              const float* __restrict__ lt0,
                              const float* __restrict__ lb0,
                              float* __restrict__ y) {
    int i = blockIdx.x * blockDim.x + threadIdx.x;  // over N*64
    int v = i >> 6, c = i & 63;
    y[i] = risk[v] * lt0[c] + lb0[c];
}

// ---------------------------------------------------------------------------
// Sparse gather: dst[u,:] = scale[u] * (optionally labelv[u] *) sum_{s in list(u)} src[s,:]
// Used for both H^T @ y (CSC) and H @ edge (CSR). float4-vectorized columns.
template<int C, bool MUL_LABEL>
__global__ void k_gather(const float* __restrict__ src, float* __restrict__ dst,
                         const int* __restrict__ idx, const int* __restrict__ cnt,
                         const float* __restrict__ scale,
                         const float* __restrict__ labelv) {
    constexpr int G = C / 4;          // lanes per unit
    constexpr int UPB = 256 / G;      // units per block
    int tid = threadIdx.x;
    int u = blockIdx.x * UPB + tid / G;
    int c4 = tid % G;
    int n = cnt[u];
    if (n > CAP) n = CAP;
    const int* lst = idx + (size_t)u * CAP;
    float4 acc = {0.f, 0.f, 0.f, 0.f};
    for (int i = 0; i < n; ++i) {
        int s = lst[i];
        float4 val = *reinterpret_cast<const float4*>(src + (size_t)s * C + c4 * 4);
        acc.x += val.x; acc.y += val.y; acc.z += val.z; acc.w += val.w;
    }
    float sc = scale[u];
    if constexpr (MUL_LABEL) sc *= labelv[u];
    acc.x *= sc; acc.y *= sc; acc.z *= sc; acc.w *= sc;
    *reinterpret_cast<float4*>(dst + (size_t)u * C + c4 * 4) = acc;
}

// ---------------------------------------------------------------------------
// Y[r, :] = X[r, :] @ W + b    (f32 vector GEMM; CIN,COUT in {64,128})
template<int CIN, int COUT>
__global__ void k_gemm(const float* __restrict__ X, const float* __restrict__ W,
                       const float* __restrict__ b, float* __restrict__ Y) {
    constexpr int G = COUT / 4;       // lanes per row
    constexpr int RPB = 256 / G;      // rows per block
    __shared__ float xs[RPB][CIN];
    int tid = threadIdx.x;
    int r0 = blockIdx.x * RPB;
    for (int i = tid; i < RPB * CIN; i += 256) {
        int rr = i / CIN, kk = i % CIN;
        xs[rr][kk] = X[(size_t)(r0 + rr) * CIN + kk];
    }
    __syncthreads();
    int g = tid / G;
    int c4 = tid % G;
    float4 acc = *reinterpret_cast<const float4*>(b + c4 * 4);
    #pragma unroll 8
    for (int k = 0; k < CIN; ++k) {
        float4 w = *reinterpret_cast<const float4*>(W + (size_t)k * COUT + c4 * 4);
        float xv = xs[g][k];
        acc.x += xv * w.x; acc.y += xv * w.y; acc.z += xv * w.z; acc.w += xv * w.w;
    }
    *reinterpret_cast<float4*>(Y + (size_t)(r0 + g) * COUT + c4 * 4) = acc;
}

// labelv[v] = sum_c lab[v,c]*fcw[c] + fcb   (C=64, one wave per row)
__global__ void k_fc_label(const float* __restrict__ lab, const float* __restrict__ fcw,
                           const float* __restrict__ fcb, float* __restrict__ labelv) {
    int wave = threadIdx.x >> 6, lane = threadIdx.x & 63;
    int v = blockIdx.x * 4 + wave;
    float val = lab[(size_t)v * 64 + lane] * fcw[lane];
    #pragma unroll
    for (int off = 32; off; off >>= 1) val += __shfl_down(val, off);
    if (lane == 0) labelv[v] = val + fcb[0];
}

// out0[v] = fts[v,:] @ w3 + b3 ; out1[v] = out0[v] + risk[v]  (one wave per row)
__global__ void k_final(const float* __restrict__ fts, const float* __restrict__ w3,
                        const float* __restrict__ b3, const float* __restrict__ risk,
                        float* __restrict__ out0, float* __restrict__ out1) {
    int wave = threadIdx.x >> 6, lane = threadIdx.x & 63;
    int v = blockIdx.x * 4 + wave;
    float val = fts[(size_t)v * 128 + lane] * w3[lane]
              + fts[(size_t)v * 128 + 64 + lane] * w3[64 + lane];
    #pragma unroll
    for (int off = 32; off; off >>= 1) val += __shfl_down(val, off);
    if (lane == 0) {
        float o = val + b3[0];
        out0[v] = o;
        out1[v] = o + risk[v];
    }
}

// ---------------------------------------------------------------------------
extern "C" void kernel_launch(void* const* d_in, const int* in_sizes, int n_in,
                              void* d_out, int out_size, void* d_ws, size_t ws_size,
                              hipStream_t stream) {
    const float* x    = (const float*)d_in[0];
    const float* risk = (const float*)d_in[1];
    const float* H    = (const float*)d_in[2];
    const float* th0  = (const float*)d_in[3];
    const float* b0   = (const float*)d_in[4];
    const float* th1  = (const float*)d_in[5];
    const float* b1   = (const float*)d_in[6];
    const float* lt0  = (const float*)d_in[7];
    const float* lb0  = (const float*)d_in[8];
    const float* lt1  = (const float*)d_in[9];
    const float* lb1  = (const float*)d_in[10];
    const float* fcw  = (const float*)d_in[11];
    const float* fcb  = (const float*)d_in[12];
    const float* w1   = (const float*)d_in[13];
    const float* bw1  = (const float*)d_in[14];
    const float* w2   = (const float*)d_in[15];
    const float* bw2  = (const float*)d_in[16];
    const float* w3   = (const float*)d_in[17];
    const float* bw3  = (const float*)d_in[18];
    float* out = (float*)d_out;

    // Workspace layout (all 64KB-aligned chunks; total ~34 MB)
    int*   row_cnt = (int*)d_ws;                 // N
    int*   col_cnt = row_cnt + N;                // N
    int*   rowIdx  = col_cnt + N;                // N*CAP
    int*   colIdx  = rowIdx + (size_t)N * CAP;   // N*CAP
    float* dv_inv  = (float*)(colIdx + (size_t)N * CAP);  // N
    float* de_inv  = dv_inv + N;                 // N
    float* labelv  = de_inv + N;                 // N
    float* F1      = labelv + N;                 // N*128
    float* F2      = F1 + (size_t)N * 128;       // N*128
    float* F3      = F2 + (size_t)N * 128;       // N*128

    // 1. Build sparse structure from dense H (the 1 GiB read)
    k_zero<<<(2 * N + 255) / 256, 256, 0, stream>>>(row_cnt, 2 * N);
    k_scan_H<<<N, 256, 0, stream>>>(H, row_cnt, col_cnt, rowIdx, colIdx);
    k_inv<<<(N + 255) / 256, 256, 0, stream>>>(row_cnt, col_cnt, dv_inv, de_inv);

    // 2. Label branch (C=64)
    k_outer_label<<<(N * 64) / 256, 256, 0, stream>>>(risk, lt0, lb0, F1);
    k_gather<64, false><<<N / 16, 256, 0, stream>>>(F1, F2, colIdx, col_cnt, de_inv, nullptr);
    k_gather<64, false><<<N / 16, 256, 0, stream>>>(F2, F3, rowIdx, row_cnt, dv_inv, nullptr);
    k_gemm<64, 64><<<N / 16, 256, 0, stream>>>(F3, lt1, lb1, F1);
    k_gather<64, false><<<N / 16, 256, 0, stream>>>(F1, F2, colIdx, col_cnt, de_inv, nullptr);
    k_gather<64, false><<<N / 16, 256, 0, stream>>>(F2, F3, rowIdx, row_cnt, dv_inv, nullptr);
    k_fc_label<<<N / 4, 256, 0, stream>>>(F3, fcw, fcb, labelv);

    // 3. Feature branch (C=128)
    k_gemm<128, 128><<<N / 8, 256, 0, stream>>>(x, th0, b0, F1);
    k_gather<128, false><<<N / 8, 256, 0, stream>>>(F1, F2, colIdx, col_cnt, de_inv, nullptr);
    k_gather<128, false><<<N / 8, 256, 0, stream>>>(F2, F3, rowIdx, row_cnt, dv_inv, nullptr);
    k_gemm<128, 128><<<N / 8, 256, 0, stream>>>(F3, th1, b1, F1);
    k_gather<128, false><<<N / 8, 256, 0, stream>>>(F1, F2, colIdx, col_cnt, de_inv, nullptr);
    k_gather<128, true><<<N / 8, 256, 0, stream>>>(F2, F3, rowIdx, row_cnt, dv_inv, labelv);
    k_gemm<128, 128><<<N / 8, 256, 0, stream>>>(F3, w1, bw1, F1);
    k_gemm<128, 128><<<N / 8, 256, 0, stream>>>(F1, w2, bw2, out + 2 * N);   // fts
    k_final<<<N / 4, 256, 0, stream>>>(out + 2 * N, w3, bw3, risk, out, out + N);
}

// Round 2
// 485.313 us; speedup vs baseline: 1.1029x; 1.1029x over previous
//
#include <hip/hip_runtime.h>
#include <hip/hip_fp16.h>

#define N 16384
#define CAP 64   // max tracked nnz per row/col of H (Poisson(17) -> max ~40)

// ---------------------------------------------------------------------------
__global__ void k_zero(int* __restrict__ p, int n) {
    int i = blockIdx.x * blockDim.x + threadIdx.x;
    if (i < n) p[i] = 0;
}

// ---------------------------------------------------------------------------
// Single streaming pass over dense H (1 GiB): builds CSR (rowIdx/row_cnt) and
// CSC (colIdx/col_cnt). H binary => counts == degree sums.
__global__ void k_scan_H(const float* __restrict__ H,
                         int* __restrict__ row_cnt, int* __restrict__ col_cnt,
                         int* __restrict__ rowIdx, int* __restrict__ colIdx) {
    __shared__ int rc;
    int v = blockIdx.x;
    if (threadIdx.x == 0) rc = 0;
    __syncthreads();
    const float4* row = reinterpret_cast<const float4*>(H + (size_t)v * N);
    #pragma unroll 4
    for (int i = 0; i < 16; ++i) {
        int idx4 = i * 256 + threadIdx.x;
        float4 val = row[idx4];
        int e0 = idx4 * 4;
        float vals[4] = {val.x, val.y, val.z, val.w};
        #pragma unroll
        for (int j = 0; j < 4; ++j) {
            if (vals[j] != 0.0f) {
                int e = e0 + j;
                int p = atomicAdd(&rc, 1);
                if (p < CAP) rowIdx[(size_t)v * CAP + p] = e;
                int q = atomicAdd(&col_cnt[e], 1);
                if (q < CAP) colIdx[(size_t)e * CAP + q] = v;
            }
        }
    }
    __syncthreads();
    if (threadIdx.x == 0) row_cnt[v] = rc;
}

// ---------------------------------------------------------------------------
// Label-branch coefficients: p = lt0 @ lt1, q = lb0 @ lt1 + lb1,
// alpha = p.fcw, beta = q.fcw + fcb.  One 64-thread block.
__global__ void k_coef(const float* __restrict__ lt0, const float* __restrict__ lb0,
                       const float* __restrict__ lt1, const float* __restrict__ lb1,
                       const float* __restrict__ fcw, const float* __restrict__ fcb,
                       float* __restrict__ ab) {
    int c = threadIdx.x;  // 0..63
    float p = 0.f, q = 0.f;
    #pragma unroll 8
    for (int k = 0; k < 64; ++k) {
        float w = lt1[k * 64 + c];
        p += lt0[k] * w;
        q += lb0[k] * w;
    }
    q += lb1[c];
    float pa = p * fcw[c];
    float qb = q * fcw[c];
    #pragma unroll
    for (int off = 32; off; off >>= 1) {
        pa += __shfl_down(pa, off);
        qb += __shfl_down(qb, off);
    }
    if (c == 0) { ab[0] = pa; ab[1] = qb + fcb[0]; }
}

// Scalar degree-normalized aggregation stage: t[u] = (1/cnt[u]) * sum z[lst]
// (optionally affine: alpha*t + beta for the final label output).
template<bool AFFINE>
__global__ void k_agg(const float* __restrict__ z, float* __restrict__ t,
                      const int* __restrict__ idx, const int* __restrict__ cnt,
                      const float* __restrict__ ab) {
    int u = blockIdx.x * 256 + threadIdx.x;
    int n = cnt[u];
    float inv = 1.0f / (float)n;
    if (n > CAP) n = CAP;
    const int* lst = idx + (size_t)u * CAP;
    float s = 0.f;
    for (int i = 0; i < n; ++i) s += z[lst[i]];
    s *= inv;
    if constexpr (AFFINE) s = ab[0] * s + ab[1];
    t[u] = s;
}

// ---------------------------------------------------------------------------
// Feature gather (C=128, fp16 storage, f32 accumulation):
// dst[u,:] = (1/cnt[u]) * (optionally labelv[u] *) sum_{s in list} src[s,:]
// 16 lanes/node, 8 halfs (16B) per lane.
template<bool MUL_LABEL>
__global__ void k_gather_h(const __half* __restrict__ src, __half* __restrict__ dst,
                           const int* __restrict__ idx, const int* __restrict__ cnt,
                           const float* __restrict__ labelv) {
    int tid = threadIdx.x;
    int u = blockIdx.x * 16 + (tid >> 4);
    int c8 = tid & 15;
    int n = cnt[u];
    float inv = 1.0f / (float)n;
    if (n > CAP) n = CAP;
    const int* lst = idx + (size_t)u * CAP;
    float acc[8] = {0.f, 0.f, 0.f, 0.f, 0.f, 0.f, 0.f, 0.f};
    for (int i = 0; i < n; ++i) {
        int s = lst[i];
        uint4 raw = *reinterpret_cast<const uint4*>(src + (size_t)s * 128 + c8 * 8);
        const __half2* h = reinterpret_cast<const __half2*>(&raw);
        #pragma unroll
        for (int j = 0; j < 4; ++j) {
            float2 f = __half22float2(h[j]);
            acc[2 * j]     += f.x;
            acc[2 * j + 1] += f.y;
        }
    }
    float sc = inv;
    if constexpr (MUL_LABEL) sc *= labelv[u];
    uint4 outv;
    __half2* oh = reinterpret_cast<__half2*>(&outv);
    #pragma unroll
    for (int j = 0; j < 4; ++j)
        oh[j] = __floats2half2_rn(acc[2 * j] * sc, acc[2 * j + 1] * sc);
    *reinterpret_cast<uint4*>(dst + (size_t)u * 128 + c8 * 8) = outv;
}

// ---------------------------------------------------------------------------
// 128x128 GEMM, f32 accumulate; templated input/output element type.
// 8 rows/block; 32 lanes (float4) per row over 128 outputs.
template<bool IN16, bool OUT16>
__global__ void k_gemm128(const void* __restrict__ Xv, const float* __restrict__ W,
                          const float* __restrict__ b, void* __restrict__ Yv) {
    __shared__ float xs[8][128];
    int tid = threadIdx.x;
    int r0 = blockIdx.x * 8;
    {
        int i = tid * 4;
        int rr = i >> 7, kk = i & 127;
        if constexpr (IN16) {
            const __half* X = (const __half*)Xv;
            uint2 raw = *reinterpret_cast<const uint2*>(X + (size_t)(r0 + rr) * 128 + kk);
            const __half2* h = reinterpret_cast<const __half2*>(&raw);
            float2 f0 = __half22float2(h[0]), f1 = __half22float2(h[1]);
            xs[rr][kk] = f0.x; xs[rr][kk + 1] = f0.y;
            xs[rr][kk + 2] = f1.x; xs[rr][kk + 3] = f1.y;
        } else {
            const float* X = (const float*)Xv;
            float4 raw = *reinterpret_cast<const float4*>(X + (size_t)(r0 + rr) * 128 + kk);
            xs[rr][kk] = raw.x; xs[rr][kk + 1] = raw.y;
            xs[rr][kk + 2] = raw.z; xs[rr][kk + 3] = raw.w;
        }
    }
    __syncthreads();
    int g = tid >> 5;
    int c4 = tid & 31;
    float4 acc = *reinterpret_cast<const float4*>(b + c4 * 4);
    #pragma unroll 8
    for (int k = 0; k < 128; ++k) {
        float4 w = *reinterpret_cast<const float4*>(W + (size_t)k * 128 + c4 * 4);
        float xv = xs[g][k];
        acc.x += xv * w.x; acc.y += xv * w.y; acc.z += xv * w.z; acc.w += xv * w.w;
    }
    if constexpr (OUT16) {
        __half* Y = (__half*)Yv;
        uint2 o;
        __half2* oh = reinterpret_cast<__half2*>(&o);
        oh[0] = __floats2half2_rn(acc.x, acc.y);
        oh[1] = __floats2half2_rn(acc.z, acc.w);
        *reinterpret_cast<uint2*>(Y + (size_t)(r0 + g) * 128 + c4 * 4) = o;
    } else {
        float* Y = (float*)Yv;
        *reinterpret_cast<float4*>(Y + (size_t)(r0 + g) * 128 + c4 * 4) = acc;
    }
}

// out0[v] = fts[v,:] @ w3 + b3 ; out1[v] = out0[v] + risk[v]  (one wave/row)
__global__ void k_final(const float* __restrict__ fts, const float* __restrict__ w3,
                        const float* __restrict__ b3, const float* __restrict__ risk,
                        float* __restrict__ out0, float* __restrict__ out1) {
    int wave = threadIdx.x >> 6, lane = threadIdx.x & 63;
    int v = blockIdx.x * 4 + wave;
    float val = fts[(size_t)v * 128 + lane] * w3[lane]
              + fts[(size_t)v * 128 + 64 + lane] * w3[64 + lane];
    #pragma unroll
    for (int off = 32; off; off >>= 1) val += __shfl_down(val, off);
    if (lane == 0) {
        float o = val + b3[0];
        out0[v] = o;
        out1[v] = o + risk[v];
    }
}

// ---------------------------------------------------------------------------
extern "C" void kernel_launch(void* const* d_in, const int* in_sizes, int n_in,
                              void* d_out, int out_size, void* d_ws, size_t ws_size,
                              hipStream_t stream) {
    const float* x    = (const float*)d_in[0];
    const float* risk = (const float*)d_in[1];
    const float* H    = (const float*)d_in[2];
    const float* th0  = (const float*)d_in[3];
    const float* b0   = (const float*)d_in[4];
    const float* th1  = (const float*)d_in[5];
    const float* b1   = (const float*)d_in[6];
    const float* lt0  = (const float*)d_in[7];
    const float* lb0  = (const float*)d_in[8];
    const float* lt1  = (const float*)d_in[9];
    const float* lb1  = (const float*)d_in[10];
    const float* fcw  = (const float*)d_in[11];
    const float* fcb  = (const float*)d_in[12];
    const float* w1   = (const float*)d_in[13];
    const float* bw1  = (const float*)d_in[14];
    const float* w2   = (const float*)d_in[15];
    const float* bw2  = (const float*)d_in[16];
    const float* w3   = (const float*)d_in[17];
    const float* bw3  = (const float*)d_in[18];
    float* out = (float*)d_out;

    // Workspace layout (byte offsets, 64KB-aligned chunks)
    char* ws = (char*)d_ws;
    int*   row_cnt = (int*)(ws);                       // N ints (64KB)
    int*   col_cnt = (int*)(ws + (1 << 16));           // N ints
    int*   rowIdx  = (int*)(ws + (2 << 16));           // N*CAP ints (4MB)
    int*   colIdx  = (int*)(ws + (2 << 16) + (N * CAP * 4));
    char*  ws2     = ws + (2 << 16) + 2 * (size_t)N * CAP * 4;
    float* ab      = (float*)(ws2);                    // 2 floats
    float* tE      = (float*)(ws2 + (1 << 16));        // N floats
    float* tA      = (float*)(ws2 + (2 << 16));        // N floats
    float* labelv  = (float*)(ws2 + (3 << 16));        // N floats
    __half* F1h    = (__half*)(ws2 + (4 << 16));                 // N*128 halfs (4MB)
    __half* F2h    = (__half*)(ws2 + (4 << 16) + (N * 128 * 2)); // 4MB
    __half* F3h    = (__half*)(ws2 + (4 << 16) + 2 * (N * 128 * 2));

    // 1. Sparse structure from dense H (the 1 GiB read — HBM floor)
    k_zero<<<(2 * N + 255) / 256, 256, 0, stream>>>(row_cnt, 2 * N);
    k_scan_H<<<N, 256, 0, stream>>>(H, row_cnt, col_cnt, rowIdx, colIdx);

    // 2. Label branch — collapsed to scalar aggregations + affine
    k_coef<<<1, 64, 0, stream>>>(lt0, lb0, lt1, lb1, fcw, fcb, ab);
    k_agg<false><<<N / 256, 256, 0, stream>>>(risk, tE, colIdx, col_cnt, nullptr);
    k_agg<false><<<N / 256, 256, 0, stream>>>(tE, tA, rowIdx, row_cnt, nullptr);
    k_agg<false><<<N / 256, 256, 0, stream>>>(tA, tE, colIdx, col_cnt, nullptr);
    k_agg<true><<<N / 256, 256, 0, stream>>>(tE, labelv, rowIdx, row_cnt, ab);

    // 3. Feature branch (C=128, fp16 intermediates, f32 accumulation)
    k_gemm128<false, true><<<N / 8, 256, 0, stream>>>(x, th0, b0, F1h);
    k_gather_h<false><<<N / 16, 256, 0, stream>>>(F1h, F2h, colIdx, col_cnt, nullptr);
    k_gather_h<false><<<N / 16, 256, 0, stream>>>(F2h, F3h, rowIdx, row_cnt, nullptr);
    k_gemm128<true, true><<<N / 8, 256, 0, stream>>>(F3h, th1, b1, F1h);
    k_gather_h<false><<<N / 16, 256, 0, stream>>>(F1h, F2h, colIdx, col_cnt, nullptr);
    k_gather_h<true><<<N / 16, 256, 0, stream>>>(F2h, F3h, rowIdx, row_cnt, labelv);
    k_gemm128<true, true><<<N / 8, 256, 0, stream>>>(F3h, w1, bw1, F1h);
    k_gemm128<true, false><<<N / 8, 256, 0, stream>>>(F1h, w2, bw2, out + 2 * N);  // fts
    k_final<<<N / 4, 256, 0, stream>>>(out + 2 * N, w3, bw3, risk, out, out + N);
}

// Round 3
// 412.423 us; speedup vs baseline: 1.2978x; 1.1767x over previous
//
#include <hip/hip_runtime.h>
#include <hip/hip_fp16.h>

#define N 16384
#define CAP 64   // max tracked nnz per row/col of H (Poisson(17) -> max ~40)

typedef float f4 __attribute__((ext_vector_type(4)));

// ---------------------------------------------------------------------------
// init: zero the 2N degree counters; block 128 also computes the collapsed
// label-branch affine coefficients: label = ab[0]*agg2(agg2(risk)) + ab[1].
__global__ void k_init(int* __restrict__ cnts,
                       const float* __restrict__ lt0, const float* __restrict__ lb0,
                       const float* __restrict__ lt1, const float* __restrict__ lb1,
                       const float* __restrict__ fcw, const float* __restrict__ fcb,
                       float* __restrict__ ab) {
    if (blockIdx.x < 128) {
        cnts[blockIdx.x * 256 + threadIdx.x] = 0;
    } else if (threadIdx.x < 64) {
        int c = threadIdx.x;
        float p = 0.f, q = 0.f;
        #pragma unroll 8
        for (int k = 0; k < 64; ++k) {
            float w = lt1[k * 64 + c];
            p += lt0[k] * w;
            q += lb0[k] * w;
        }
        q += lb1[c];
        float pa = p * fcw[c];
        float qb = q * fcw[c];
        #pragma unroll
        for (int off = 32; off; off >>= 1) {
            pa += __shfl_down(pa, off);
            qb += __shfl_down(qb, off);
        }
        if (c == 0) { ab[0] = pa; ab[1] = qb + fcb[0]; }
    }
}

// ---------------------------------------------------------------------------
// Mega kernel: blocks [0,2048) do the first feature GEMM (x @ th0 + b0 -> F1h,
// fp16 out); blocks [2048, 2048+N) stream one row of dense H each, building
// CSR (rowIdx/row_cnt) and CSC (colIdx/col_cnt). The GEMM hides under the
// scan's 1 GiB HBM read.
__global__ void k_mega(const float* __restrict__ H,
                       int* __restrict__ row_cnt, int* __restrict__ col_cnt,
                       int* __restrict__ rowIdx, int* __restrict__ colIdx,
                       const float* __restrict__ x, const float* __restrict__ th0,
                       const float* __restrict__ b0, __half* __restrict__ F1h) {
    if (blockIdx.x < 2048) {
        __shared__ float xs[8][128];
        int tid = threadIdx.x;
        int r0 = blockIdx.x * 8;
        {
            int i = tid * 4, rr = i >> 7, kk = i & 127;
            f4 raw = *reinterpret_cast<const f4*>(x + (size_t)(r0 + rr) * 128 + kk);
            xs[rr][kk] = raw.x; xs[rr][kk + 1] = raw.y;
            xs[rr][kk + 2] = raw.z; xs[rr][kk + 3] = raw.w;
        }
        __syncthreads();
        int g = tid >> 5, c4 = tid & 31;
        f4 acc = *reinterpret_cast<const f4*>(b0 + c4 * 4);
        #pragma unroll 8
        for (int k = 0; k < 128; ++k) {
            f4 w = *reinterpret_cast<const f4*>(th0 + (size_t)k * 128 + c4 * 4);
            acc += xs[g][k] * w;
        }
        uint2 o;
        __half2* oh = reinterpret_cast<__half2*>(&o);
        oh[0] = __floats2half2_rn(acc.x, acc.y);
        oh[1] = __floats2half2_rn(acc.z, acc.w);
        *reinterpret_cast<uint2*>(F1h + (size_t)(r0 + g) * 128 + c4 * 4) = o;
    } else {
        __shared__ int rc;
        int v = blockIdx.x - 2048;
        if (threadIdx.x == 0) rc = 0;
        __syncthreads();
        const f4* row = reinterpret_cast<const f4*>(H + (size_t)v * N);
        #pragma unroll 4
        for (int i = 0; i < 16; ++i) {
            int idx4 = i * 256 + threadIdx.x;
            f4 val = __builtin_nontemporal_load(row + idx4);
            int e0 = idx4 * 4;
            float vals[4] = {val.x, val.y, val.z, val.w};
            #pragma unroll
            for (int j = 0; j < 4; ++j) {
                if (vals[j] != 0.0f) {
                    int e = e0 + j;
                    int p = atomicAdd(&rc, 1);
                    if (p < CAP) rowIdx[(size_t)v * CAP + p] = e;
                    int q = atomicAdd(&col_cnt[e], 1);
                    if (q < CAP) colIdx[(size_t)e * CAP + q] = v;
                }
            }
        }
        __syncthreads();
        if (threadIdx.x == 0) row_cnt[v] = rc;
    }
}

// ---------------------------------------------------------------------------
// Fused gather: feature aggregation (C=128, fp16 storage, f32 accum) plus the
// scalar label-branch aggregation riding the same index list.
//   dst[u,:] = (1/cnt[u]) * sum src[lst,:]        (times inline label if FINAL)
//   !FINAL:  zdst[u] = (1/cnt[u]) * sum zsrc[lst]
//   FINAL:   label   = ab0*( (1/cnt[u]) * sum zsrc[lst] ) + ab1, scales dst.
template<bool FINAL>
__global__ void k_gather(const __half* __restrict__ src, __half* __restrict__ dst,
                         const int* __restrict__ idx, const int* __restrict__ cnt,
                         const float* __restrict__ zsrc, float* __restrict__ zdst,
                         const float* __restrict__ ab) {
    int tid = threadIdx.x;
    int u = blockIdx.x * 16 + (tid >> 4);
    int c8 = tid & 15;
    int n0 = cnt[u];
    float inv = 1.0f / (float)n0;
    int n = n0 > CAP ? CAP : n0;
    const int* lst = idx + (size_t)u * CAP;
    float acc[8] = {0.f, 0.f, 0.f, 0.f, 0.f, 0.f, 0.f, 0.f};
    float zs = 0.f;
    for (int i = 0; i < n; ++i) {
        int s = lst[i];
        zs += zsrc[s];
        uint4 raw = *reinterpret_cast<const uint4*>(src + (size_t)s * 128 + c8 * 8);
        const __half2* h = reinterpret_cast<const __half2*>(&raw);
        #pragma unroll
        for (int j = 0; j < 4; ++j) {
            float2 f = __half22float2(h[j]);
            acc[2 * j]     += f.x;
            acc[2 * j + 1] += f.y;
        }
    }
    float sc = inv;
    if constexpr (FINAL) {
        sc *= (ab[0] * (zs * inv) + ab[1]);
    } else {
        if (c8 == 0) zdst[u] = zs * inv;
    }
    uint4 outv;
    __half2* oh = reinterpret_cast<__half2*>(&outv);
    #pragma unroll
    for (int j = 0; j < 4; ++j)
        oh[j] = __floats2half2_rn(acc[2 * j] * sc, acc[2 * j + 1] * sc);
    *reinterpret_cast<uint4*>(dst + (size_t)u * 128 + c8 * 8) = outv;
}

// ---------------------------------------------------------------------------
// 128x128 GEMM, fp16 in/out, f32 accumulate (the th1 layer).
__global__ void k_gemm_h(const __half* __restrict__ X, const float* __restrict__ W,
                         const float* __restrict__ b, __half* __restrict__ Y) {
    __shared__ float xs[8][128];
    int tid = threadIdx.x;
    int r0 = blockIdx.x * 8;
    {
        int i = tid * 4, rr = i >> 7, kk = i & 127;
        uint2 raw = *reinterpret_cast<const uint2*>(X + (size_t)(r0 + rr) * 128 + kk);
        const __half2* h = reinterpret_cast<const __half2*>(&raw);
        float2 f0 = __half22float2(h[0]), f1 = __half22float2(h[1]);
        xs[rr][kk] = f0.x; xs[rr][kk + 1] = f0.y;
        xs[rr][kk + 2] = f1.x; xs[rr][kk + 3] = f1.y;
    }
    __syncthreads();
    int g = tid >> 5, c4 = tid & 31;
    f4 acc = *reinterpret_cast<const f4*>(b + c4 * 4);
    #pragma unroll 8
    for (int k = 0; k < 128; ++k) {
        f4 w = *reinterpret_cast<const f4*>(W + (size_t)k * 128 + c4 * 4);
        acc += xs[g][k] * w;
    }
    uint2 o;
    __half2* oh = reinterpret_cast<__half2*>(&o);
    oh[0] = __floats2half2_rn(acc.x, acc.y);
    oh[1] = __floats2half2_rn(acc.z, acc.w);
    *reinterpret_cast<uint2*>(Y + (size_t)(r0 + g) * 128 + c4 * 4) = o;
}

// ---------------------------------------------------------------------------
// Fused tail: h1 = F@w1+b1 ; fts = h1@w2+b2 (stored to out[2N..]) ;
// o = fts@w3+b3 -> out[0..N) ; out[N..2N) = o + risk.
__global__ void k_tail(const __half* __restrict__ F,
                       const float* __restrict__ w1, const float* __restrict__ b1,
                       const float* __restrict__ w2, const float* __restrict__ b2,
                       const float* __restrict__ w3, const float* __restrict__ b3,
                       const float* __restrict__ risk, float* __restrict__ out) {
    __shared__ float xs[8][128];
    __shared__ float ys[8][128];
    int tid = threadIdx.x;
    int r0 = blockIdx.x * 8;
    {
        int i = tid * 4, rr = i >> 7, kk = i & 127;
        uint2 raw = *reinterpret_cast<const uint2*>(F + (size_t)(r0 + rr) * 128 + kk);
        const __half2* h = reinterpret_cast<const __half2*>(&raw);
        float2 f0 = __half22float2(h[0]), f1 = __half22float2(h[1]);
        xs[rr][kk] = f0.x; xs[rr][kk + 1] = f0.y;
        xs[rr][kk + 2] = f1.x; xs[rr][kk + 3] = f1.y;
    }
    __syncthreads();
    int g = tid >> 5, c4 = tid & 31;
    f4 acc = *reinterpret_cast<const f4*>(b1 + c4 * 4);
    #pragma unroll 8
    for (int k = 0; k < 128; ++k) {
        f4 w = *reinterpret_cast<const f4*>(w1 + (size_t)k * 128 + c4 * 4);
        acc += xs[g][k] * w;
    }
    *reinterpret_cast<f4*>(&ys[g][c4 * 4]) = acc;
    __syncthreads();
    f4 acc2 = *reinterpret_cast<const f4*>(b2 + c4 * 4);
    #pragma unroll 8
    for (int k = 0; k < 128; ++k) {
        f4 w = *reinterpret_cast<const f4*>(w2 + (size_t)k * 128 + c4 * 4);
        acc2 += ys[g][k] * w;
    }
    int v = r0 + g;
    *reinterpret_cast<f4*>(out + 2 * (size_t)N + (size_t)v * 128 + c4 * 4) = acc2;  // fts
    f4 wv = *reinterpret_cast<const f4*>(w3 + c4 * 4);
    float val = acc2.x * wv.x + acc2.y * wv.y + acc2.z * wv.z + acc2.w * wv.w;
    #pragma unroll
    for (int off = 16; off; off >>= 1) val += __shfl_down(val, off, 32);
    if (c4 == 0) {
        float o = val + b3[0];
        out[v] = o;
        out[N + v] = o + risk[v];
    }
}

// ---------------------------------------------------------------------------
extern "C" void kernel_launch(void* const* d_in, const int* in_sizes, int n_in,
                              void* d_out, int out_size, void* d_ws, size_t ws_size,
                              hipStream_t stream) {
    const float* x    = (const float*)d_in[0];
    const float* risk = (const float*)d_in[1];
    const float* H    = (const float*)d_in[2];
    const float* th0  = (const float*)d_in[3];
    const float* b0   = (const float*)d_in[4];
    const float* th1  = (const float*)d_in[5];
    const float* b1   = (const float*)d_in[6];
    const float* lt0  = (const float*)d_in[7];
    const float* lb0  = (const float*)d_in[8];
    const float* lt1  = (const float*)d_in[9];
    const float* lb1  = (const float*)d_in[10];
    const float* fcw  = (const float*)d_in[11];
    const float* fcb  = (const float*)d_in[12];
    const float* w1   = (const float*)d_in[13];
    const float* bw1  = (const float*)d_in[14];
    const float* w2   = (const float*)d_in[15];
    const float* bw2  = (const float*)d_in[16];
    const float* w3   = (const float*)d_in[17];
    const float* bw3  = (const float*)d_in[18];
    float* out = (float*)d_out;

    // Workspace layout
    char* ws = (char*)d_ws;
    int*   row_cnt = (int*)(ws);                   // 64KB  (row_cnt/col_cnt contiguous!)
    int*   col_cnt = (int*)(ws + (1 << 16));       // 64KB
    float* ab      = (float*)(ws + (2 << 16));     // 2 floats
    float* tE      = (float*)(ws + (3 << 16));     // N floats
    float* tA      = (float*)(ws + (4 << 16));     // N floats
    int*   rowIdx  = (int*)(ws + (5 << 16));                           // 4MB
    int*   colIdx  = (int*)(ws + (5 << 16) + (size_t)N * CAP * 4);     // 4MB
    char*  wsF     = ws + (5 << 16) + 2 * (size_t)N * CAP * 4;
    __half* F1h    = (__half*)(wsF);                                   // 4MB
    __half* F2h    = (__half*)(wsF + (size_t)N * 128 * 2);             // 4MB
    __half* F3h    = (__half*)(wsF + 2 * (size_t)N * 128 * 2);         // 4MB

    // 1. init (zero counters + label coefficients)
    k_init<<<129, 256, 0, stream>>>(row_cnt, lt0, lb0, lt1, lb1, fcw, fcb, ab);

    // 2. scan H (1 GiB HBM floor) with first GEMM hidden under it
    k_mega<<<2048 + N, 256, 0, stream>>>(H, row_cnt, col_cnt, rowIdx, colIdx,
                                         x, th0, b0, F1h);

    // 3. hyconv1: edge (CSC) then node (CSR); label agg rides along
    k_gather<false><<<N / 16, 256, 0, stream>>>(F1h, F2h, colIdx, col_cnt, risk, tE, nullptr);
    k_gather<false><<<N / 16, 256, 0, stream>>>(F2h, F3h, rowIdx, row_cnt, tE, tA, nullptr);

    // 4. theta1 layer
    k_gemm_h<<<N / 8, 256, 0, stream>>>(F3h, th1, b1, F1h);

    // 5. hyconv2; final stage computes label inline and multiplies
    k_gather<false><<<N / 16, 256, 0, stream>>>(F1h, F2h, colIdx, col_cnt, tA, tE, nullptr);
    k_gather<true><<<N / 16, 256, 0, stream>>>(F2h, F3h, rowIdx, row_cnt, tE, nullptr, ab);

    // 6. fused tail: @w1 -> @w2 (fts) -> @w3 (+risk)
    k_tail<<<N / 8, 256, 0, stream>>>(F3h, w1, bw1, w2, bw2, w3, bw3, risk, out);
}